// Round 5
// baseline (2971.211 us; speedup 1.0000x reference)
//
#include <hip/hip_runtime.h>
#include <hip/hip_bf16.h>

typedef unsigned short u16;
typedef __attribute__((ext_vector_type(8))) short bf16x8;
typedef __attribute__((ext_vector_type(4))) float f32x4;

#define NB 8
#define NS 1024
#define ND 768
#define NH 12
#define NL 8
#define NDH 64
#define NV 1024
#define NCONDV 256
#define NTOK (NB*NS)

union BF8 { bf16x8 v; u16 u[8]; };
union US4 { ushort4 v; u16 u[4]; };

__device__ __forceinline__ float b2f(u16 u){ return __uint_as_float(((unsigned)u) << 16); }
__device__ __forceinline__ u16 f2b(float f){
  unsigned u = __float_as_uint(f);
  return (u16)((u + 0x7fffu + ((u >> 16) & 1u)) >> 16);   // RNE, finite inputs only
}

__device__ __forceinline__ void glds16(const u16* g, u16* l) {
  __builtin_amdgcn_global_load_lds((const __attribute__((address_space(1))) void*)g,
                                   (__attribute__((address_space(3))) void*)l, 16, 0, 0);
}

// ---------------- embedding + sinusoidal PE -> x fp32 ----------------
__global__ __launch_bounds__(256) void k_embed(const int* __restrict__ tokens,
                                               const float* __restrict__ emb,
                                               float* __restrict__ x)
{
  const int t = blockIdx.x;
  const int s = t & (NS - 1);
  const int tok = tokens[t];
  const float c = (float)(-9.210340371976184 / 768.0);
  for (int d = threadIdx.x; d < ND; d += 256) {
    float div = expf((float)(d & ~1) * c);
    float ang = (float)s * div;
    float pe = (d & 1) ? cosf(ang) : sinf(ang);
    x[(size_t)t*ND + d] = emb[(size_t)tok*ND + d] + pe;
  }
}

// ---------------- action vector ----------------
__global__ __launch_bounds__(256) void k_actvec(const int* __restrict__ actions,
                                                const float* __restrict__ act_emb,
                                                float* __restrict__ a)
{
  const int b = blockIdx.x, j = threadIdx.x;
  const int i = j >> 6, kk = j & 63;
  const int act = actions[b*4 + i];
  a[b*NCONDV + j] = act_emb[(size_t)act*64 + kk];
}

// ---------------- conditional LN gains ----------------
__global__ __launch_bounds__(256) void k_gains(const float* __restrict__ a,
    const float* __restrict__ g1, const float* __restrict__ b1,
    const float* __restrict__ g2, const float* __restrict__ b2,
    const float* __restrict__ gf, const float* __restrict__ bfp,
    float* __restrict__ outp)
{
  __shared__ float sa[NB*NCONDV];
  const int m = blockIdx.x, dc = blockIdx.y;
  for (int i = threadIdx.x; i < NB*NCONDV; i += 256) sa[i] = a[i];
  __syncthreads();
  const float* W;
  if (m < 32) {
    int ll = m >> 2, w = m & 3;
    const float* base = (w==0) ? g1 : (w==1) ? b1 : (w==2) ? g2 : b2;
    W = base + (size_t)ll * NCONDV * ND;
  } else {
    W = (m == 32) ? gf : bfp;
  }
  const int d = dc*256 + threadIdx.x;
  float acc[NB] = {0,0,0,0,0,0,0,0};
  for (int j = 0; j < NCONDV; j++) {
    float w = W[(size_t)j*ND + d];
    #pragma unroll
    for (int bb = 0; bb < NB; bb++) acc[bb] += sa[bb*NCONDV + j] * w;
  }
  #pragma unroll
  for (int bb = 0; bb < NB; bb++) outp[((size_t)m*NB + bb)*ND + d] = acc[bb];
}

// ---------------- conditional layernorm: one wave per token, no barriers ----------------
__global__ __launch_bounds__(256) void k_cln(const float* __restrict__ x,
                                             const float* __restrict__ g,
                                             const float* __restrict__ bb,
                                             u16* __restrict__ h)
{
  const int tid = threadIdx.x, w = tid >> 6, lane = tid & 63;
  const int t = blockIdx.x*4 + w;
  const int bi = t >> 10;
  const float* xr = x + (size_t)t*ND;
  f32x4 v0 = *(const f32x4*)(xr + lane*4);
  f32x4 v1 = *(const f32x4*)(xr + 256 + lane*4);
  f32x4 v2 = *(const f32x4*)(xr + 512 + lane*4);
  float s = (v0[0]+v0[1]+v0[2]+v0[3]) + (v1[0]+v1[1]+v1[2]+v1[3]) + (v2[0]+v2[1]+v2[2]+v2[3]);
  #pragma unroll
  for (int off = 1; off < 64; off <<= 1) s += __shfl_xor(s, off);
  float mu = s * (1.0f/768.0f);
  float s2 = 0.f;
  #pragma unroll
  for (int i = 0; i < 4; i++) { v0[i] -= mu; s2 += v0[i]*v0[i]; }
  #pragma unroll
  for (int i = 0; i < 4; i++) { v1[i] -= mu; s2 += v1[i]*v1[i]; }
  #pragma unroll
  for (int i = 0; i < 4; i++) { v2[i] -= mu; s2 += v2[i]*v2[i]; }
  #pragma unroll
  for (int off = 1; off < 64; off <<= 1) s2 += __shfl_xor(s2, off);
  float rs = rsqrtf(s2 * (1.0f/768.0f) + 1e-5f);
  const float* gr = g + (size_t)bi*ND;
  const float* br = bb + (size_t)bi*ND;
  u16* hr = h + (size_t)t*ND;
  #pragma unroll
  for (int j = 0; j < 3; j++) {
    f32x4 vv = (j==0) ? v0 : (j==1) ? v1 : v2;
    f32x4 gg = *(const f32x4*)(gr + j*256 + lane*4);
    f32x4 bv = *(const f32x4*)(br + j*256 + lane*4);
    US4 o;
    #pragma unroll
    for (int i = 0; i < 4; i++) o.u[i] = f2b(vv[i]*rs*gg[i] + bv[i]);
    *(ushort4*)(hr + j*256 + lane*4) = o.v;
  }
}

// ---------------- weight prep: fp32 [K][N] (xL) -> bf16 [N][K] ----------------
__global__ __launch_bounds__(256) void k_wprep(const float* __restrict__ src,
                                               u16* __restrict__ dst, int K, int N)
{
  __shared__ u16 t[64][65];
  const int k0 = blockIdx.x*64, n0 = blockIdx.y*64;
  const size_t mz = (size_t)blockIdx.z * K * N;
  src += mz; dst += mz;
  {
    int r = threadIdx.x >> 2, c0 = (threadIdx.x & 3) * 16;
    const float* s = src + (size_t)(k0 + r)*N + n0 + c0;
    f32x4 a = *(const f32x4*)s, b = *(const f32x4*)(s+4);
    f32x4 c = *(const f32x4*)(s+8), d = *(const f32x4*)(s+12);
    #pragma unroll
    for (int i = 0; i < 4; i++) {
      t[r][c0+i]    = f2b(a[i]);
      t[r][c0+4+i]  = f2b(b[i]);
      t[r][c0+8+i]  = f2b(c[i]);
      t[r][c0+12+i] = f2b(d[i]);
    }
  }
  __syncthreads();
  {
    int rn = threadIdx.x >> 2, kc = (threadIdx.x & 3)*16;
    u16* dp = dst + (size_t)(n0+rn)*K + k0 + kc;
    BF8 o0, o1;
    #pragma unroll
    for (int i = 0; i < 8; i++) { o0.u[i] = t[kc+i][rn]; o1.u[i] = t[kc+8+i][rn]; }
    *(bf16x8*)dp = o0.v; *(bf16x8*)(dp+8) = o1.v;
  }
}

// ---------------- per-head QKV projection (fp32 weights) ----------------
__global__ __launch_bounds__(256) void k_qkv(const u16* __restrict__ h,
    const float* __restrict__ Wq, const float* __restrict__ Wk, const float* __restrict__ Wv,
    u16* __restrict__ qo, u16* __restrict__ ko, u16* __restrict__ vo)
{
  __shared__ alignas(16) u16 wlds[64][72];
  const int t0 = blockIdx.x * 64, head = blockIdx.y, which = blockIdx.z;
  const float* W = ((which==0) ? Wq : (which==1) ? Wk : Wv) + (size_t)head*NDH*NDH;
  {
    int d = threadIdx.x >> 2, e0 = (threadIdx.x & 3) * 16;
    const float* wr = W + (size_t)d*NDH + e0;
    f32x4 f0 = *(const f32x4*)wr;
    f32x4 f1 = *(const f32x4*)(wr + 4);
    f32x4 f2 = *(const f32x4*)(wr + 8);
    f32x4 f3 = *(const f32x4*)(wr + 12);
    #pragma unroll
    for (int i = 0; i < 4; i++) {
      wlds[e0+i][d]    = f2b(f0[i]);
      wlds[e0+4+i][d]  = f2b(f1[i]);
      wlds[e0+8+i][d]  = f2b(f2[i]);
      wlds[e0+12+i][d] = f2b(f3[i]);
    }
  }
  __syncthreads();
  const int wave = threadIdx.x >> 6, lane = threadIdx.x & 63;
  const int lo16 = lane & 15, quad = lane >> 4;
  const int arow = t0 + wave*16 + lo16;
  const u16* hr = h + (size_t)arow*ND + head*NDH + quad*8;
  bf16x8 a0 = *(const bf16x8*)hr;
  bf16x8 a1 = *(const bf16x8*)(hr + 32);
  f32x4 acc[4] = {{0,0,0,0},{0,0,0,0},{0,0,0,0},{0,0,0,0}};
  #pragma unroll
  for (int n = 0; n < 4; n++) {
    const u16* bp = &wlds[n*16 + lo16][quad*8];
    bf16x8 b0 = *(const bf16x8*)bp;
    bf16x8 b1 = *(const bf16x8*)(bp + 32);
    acc[n] = __builtin_amdgcn_mfma_f32_16x16x32_bf16(a0, b0, acc[n], 0, 0, 0);
    acc[n] = __builtin_amdgcn_mfma_f32_16x16x32_bf16(a1, b1, acc[n], 0, 0, 0);
  }
  #pragma unroll
  for (int n = 0; n < 4; n++) {
    #pragma unroll
    for (int r = 0; r < 4; r++) {
      int t = t0 + wave*16 + quad*4 + r;
      int bb = t >> 10, s = t & (NS-1);
      int e = n*16 + lo16;
      u16 val = f2b(acc[n][r]);
      if (which == 2) {
        int local = s & 127;
        int col = (s & ~127) | (((local & 15) << 3) | (local >> 4));
        vo[(((size_t)bb*NH + head)*NDH + e)*NS + col] = val;
      } else {
        u16* dst = (which == 0) ? qo : ko;
        dst[(((size_t)bb*NH + head)*NS + s)*NDH + e] = val;
      }
    }
  }
}

// ---------------- flash attention: no-max softmax, slot-permuted P/V ----------------
__global__ __launch_bounds__(256) void k_attn2(const u16* __restrict__ q,
                                               const u16* __restrict__ kk,
                                               const u16* __restrict__ vt,
                                               u16* __restrict__ o)
{
  __shared__ alignas(16) u16 klds[128][72];
  __shared__ alignas(16) u16 vlds[64][136];
  __shared__ alignas(16) u16 plds[4][16][136];
  const int tid = threadIdx.x, w = tid >> 6, lane = tid & 63;
  const int lo16 = lane & 15, quad = lane >> 4;
  const int bh = blockIdx.x;
  const int b = bh / NH, head = bh - b*NH;
  const int q0 = blockIdx.y*64 + w*16;
  const u16* qb = q  + (size_t)bh*NS*NDH;
  const u16* kb = kk + (size_t)bh*NS*NDH;
  const u16* vb = vt + (size_t)bh*NDH*NS;
  BF8 aq0, aq1;
  {
    const u16* qr = qb + (size_t)(q0 + lo16)*NDH + quad*8;
    BF8 r0, r1; r0.v = *(const bf16x8*)qr; r1.v = *(const bf16x8*)(qr + 32);
    #pragma unroll
    for (int j = 0; j < 8; j++) {
      aq0.u[j] = f2b(b2f(r0.u[j]) * 0.125f);
      aq1.u[j] = f2b(b2f(r1.u[j]) * 0.125f);
    }
  }
  float lsum[4] = {0,0,0,0};
  f32x4 oacc[4] = {{0,0,0,0},{0,0,0,0},{0,0,0,0},{0,0,0,0}};

  for (int kt = 0; kt < NS; kt += 128) {
    __syncthreads();
    #pragma unroll
    for (int i = 0; i < 4; i++) {
      int c = tid + 256*i, row = c >> 3, cc = (c & 7)*8;
      *(bf16x8*)&klds[row][cc] = *(const bf16x8*)(kb + (size_t)(kt+row)*NDH + cc);
    }
    #pragma unroll
    for (int i = 0; i < 4; i++) {
      int c = tid + 256*i, row = c >> 4, cc = (c & 15)*8;
      *(bf16x8*)&vlds[row][cc] = *(const bf16x8*)(vb + (size_t)row*NS + kt + cc);
    }
    __syncthreads();
    f32x4 s[8];
    #pragma unroll
    for (int j = 0; j < 8; j++) {
      const u16* kr = &klds[j*16 + lo16][quad*8];
      bf16x8 b0 = *(const bf16x8*)kr;
      bf16x8 b1 = *(const bf16x8*)(kr + 32);
      f32x4 z = {0,0,0,0};
      z = __builtin_amdgcn_mfma_f32_16x16x32_bf16(aq0.v, b0, z, 0, 0, 0);
      s[j] = __builtin_amdgcn_mfma_f32_16x16x32_bf16(aq1.v, b1, z, 0, 0, 0);
    }
    #pragma unroll
    for (int r = 0; r < 4; r++) {
      BF8 pk;
      float ps = 0.f;
      #pragma unroll
      for (int j = 0; j < 8; j++) {
        float pj = __expf(s[j][r]);
        pk.u[j] = f2b(pj);
        ps += b2f(pk.u[j]);
      }
      lsum[r] += ps;
      *(bf16x8*)&plds[w][quad*4 + r][lo16*8] = pk.v;
    }
    #pragma unroll
    for (int kc = 0; kc < 4; kc++) {
      bf16x8 pa = *(const bf16x8*)&plds[w][lo16][kc*32 + quad*8];
      #pragma unroll
      for (int n = 0; n < 4; n++) {
        bf16x8 vf = *(const bf16x8*)&vlds[n*16 + lo16][kc*32 + quad*8];
        oacc[n] = __builtin_amdgcn_mfma_f32_16x16x32_bf16(pa, vf, oacc[n], 0, 0, 0);
      }
    }
  }
  #pragma unroll
  for (int r = 0; r < 4; r++) {
    #pragma unroll
    for (int off = 1; off < 16; off <<= 1) lsum[r] += __shfl_xor(lsum[r], off);
  }
  #pragma unroll
  for (int n = 0; n < 4; n++) {
    #pragma unroll
    for (int r = 0; r < 4; r++) {
      int s_ = q0 + quad*4 + r;
      int d = head*NDH + n*16 + lo16;
      o[((size_t)b*NS + s_)*ND + d] = f2b(oacc[n][r] / lsum[r]);
    }
  }
}

// ---------------- fast GEMM: 128x128 tile, BK=64, XOR-swizzled LDS, 32 MFMA/barrier ----------------
// Bt is bf16 [N][K]. EPI 0: f32=A@B+bias ; 1: bf16=gelu(A@B+bias) ; 2: f32=A@B+bias+resid
template<int EPI>
__global__ __launch_bounds__(256) void k_gemm_t(
    const u16* __restrict__ A, const u16* __restrict__ Bt,
    const float* __restrict__ bias, const float* resid,
    void* out, int M, int N, int K)
{
  __shared__ alignas(16) u16 alds[128*64];   // [m][k], odd rows have 32-element k-halves swapped
  __shared__ alignas(16) u16 blds[128*64];   // [n][k], same swizzle
  const int m0 = blockIdx.x*128, n0 = blockIdx.y*128;
  const int tid = threadIdx.x;
  const int w = tid >> 6, lane = tid & 63, lo16 = lane & 15, quad = lane >> 4;
  const int wm = (w & 1)*64, wn = (w >> 1)*64;
  f32x4 acc[4][4];
  #pragma unroll
  for (int i = 0; i < 4; i++)
    #pragma unroll
    for (int j = 0; j < 4; j++) acc[i][j] = (f32x4){0,0,0,0};
  const int r0 = tid >> 3;                       // 0..31
  const int c0 = (tid & 7) * 8;                  // 0..56
  const int csrc = c0 ^ ((r0 & 1) * 32);         // XOR bank swizzle via source column
  const u16* Ab = A  + (size_t)(m0 + r0)*K + csrc;
  const u16* Bb = Bt + (size_t)(n0 + r0)*K + csrc;
  const int xo = (lo16 & 1) * 32;                // read-side XOR for fragment rows
  for (int k0 = 0; k0 < K; k0 += 64) {
    __syncthreads();
    glds16(Ab + k0,                    alds + (size_t)tid*8);
    glds16(Ab + k0 + (size_t)32*K,     alds + 2048 + (size_t)tid*8);
    glds16(Ab + k0 + (size_t)64*K,     alds + 4096 + (size_t)tid*8);
    glds16(Ab + k0 + (size_t)96*K,     alds + 6144 + (size_t)tid*8);
    glds16(Bb + k0,                    blds + (size_t)tid*8);
    glds16(Bb + k0 + (size_t)32*K,     blds + 2048 + (size_t)tid*8);
    glds16(Bb + k0 + (size_t)64*K,     blds + 4096 + (size_t)tid*8);
    glds16(Bb + k0 + (size_t)96*K,     blds + 6144 + (size_t)tid*8);
    __syncthreads();
    #pragma unroll
    for (int kq = 0; kq < 2; kq++) {
      const int ko = (kq*32 + quad*8) ^ xo;
      bf16x8 af[4], bf[4];
      #pragma unroll
      for (int i = 0; i < 4; i++) af[i] = *(const bf16x8*)&alds[(wm + i*16 + lo16)*64 + ko];
      #pragma unroll
      for (int j = 0; j < 4; j++) bf[j] = *(const bf16x8*)&blds[(wn + j*16 + lo16)*64 + ko];
      #pragma unroll
      for (int i = 0; i < 4; i++)
        #pragma unroll
        for (int j = 0; j < 4; j++)
          acc[i][j] = __builtin_amdgcn_mfma_f32_16x16x32_bf16(af[i], bf[j], acc[i][j], 0, 0, 0);
    }
  }
  #pragma unroll
  for (int j = 0; j < 4; j++) {
    int col = n0 + wn + j*16 + lo16;
    float bv = bias[col];
    #pragma unroll
    for (int i = 0; i < 4; i++) {
      #pragma unroll
      for (int r = 0; r < 4; r++) {
        int row = m0 + wm + i*16 + quad*4 + r;
        float v = acc[i][j][r] + bv;
        if (EPI == 1) {
          float u = 0.7978845608028654f*(v + 0.044715f*v*v*v);
          float e = __expf(2.0f*u);
          float th = (e - 1.0f) / (e + 1.0f);
          ((u16*)out)[(size_t)row*N + col] = f2b(0.5f*v*(1.0f + th));
        } else if (EPI == 2) {
          ((float*)out)[(size_t)row*N + col] = v + resid[(size_t)row*N + col];
        } else {
          ((float*)out)[(size_t)row*N + col] = v;
        }
      }
    }
  }
}

// ---------------- fallback GEMM (fp32 weights, 64x64 tile) ----------------
template<int EPI>
__global__ __launch_bounds__(256) void k_gemm(
    const u16* __restrict__ A, const float* __restrict__ Bw,
    const float* __restrict__ bias, const float* resid,
    void* out, int M, int N, int K)
{
  __shared__ alignas(16) u16 alds[64][40];
  __shared__ alignas(16) u16 blds[64][40];
  const int m0 = blockIdx.x * 64, n0b = blockIdx.y * 64;
  const int tid = threadIdx.x;
  const int wave = tid >> 6, lane = tid & 63, lo16 = lane & 15, quad = lane >> 4;
  f32x4 acc[4] = {{0,0,0,0},{0,0,0,0},{0,0,0,0},{0,0,0,0}};
  const int ar = tid >> 2, ac = (tid & 3) * 8;
  const int bk = tid >> 3, bn = (tid & 7) * 8;
  for (int k0 = 0; k0 < K; k0 += 32) {
    __syncthreads();
    *(bf16x8*)&alds[ar][ac] = *(const bf16x8*)(A + (size_t)(m0+ar)*K + k0 + ac);
    {
      const float* brow = Bw + (size_t)(k0+bk)*N + n0b + bn;
      f32x4 f0 = *(const f32x4*)brow;
      f32x4 f1 = *(const f32x4*)(brow + 4);
      #pragma unroll
      for (int i = 0; i < 4; i++) {
        blds[bn+i][bk]   = f2b(f0[i]);
        blds[bn+4+i][bk] = f2b(f1[i]);
      }
    }
    __syncthreads();
    bf16x8 af = *(const bf16x8*)&alds[wave*16 + lo16][quad*8];
    #pragma unroll
    for (int n = 0; n < 4; n++) {
      bf16x8 bf = *(const bf16x8*)&blds[n*16 + lo16][quad*8];
      acc[n] = __builtin_amdgcn_mfma_f32_16x16x32_bf16(af, bf, acc[n], 0, 0, 0);
    }
  }
  const int rbase = m0 + wave*16 + quad*4;
  #pragma unroll
  for (int n = 0; n < 4; n++) {
    int col = n0b + n*16 + lo16;
    float bv = bias[col];
    #pragma unroll
    for (int r = 0; r < 4; r++) {
      int row = rbase + r;
      float v = acc[n][r] + bv;
      if (EPI == 1) {
        float x3 = v*v*v;
        v = 0.5f*v*(1.0f + tanhf(0.7978845608028654f*(v + 0.044715f*x3)));
        ((u16*)out)[(size_t)row*N + col] = f2b(v);
      } else if (EPI == 2) {
        ((float*)out)[(size_t)row*N + col] = v + resid[(size_t)row*N + col];
      } else {
        ((float*)out)[(size_t)row*N + col] = v;
      }
    }
  }
}

extern "C" void kernel_launch(void* const* d_in, const int* in_sizes, int n_in,
                              void* d_out, int out_size, void* d_ws, size_t ws_size,
                              hipStream_t stream)
{
  (void)in_sizes; (void)n_in; (void)out_size;
  const int*   tokens  = (const int*)d_in[0];
  const int*   actions = (const int*)d_in[1];
  const float* emb     = (const float*)d_in[2];
  const float* act_emb = (const float*)d_in[3];
  const float* ln1_g   = (const float*)d_in[4];
  const float* ln1_b   = (const float*)d_in[5];
  const float* Wq      = (const float*)d_in[6];
  const float* Wk      = (const float*)d_in[7];
  const float* Wv      = (const float*)d_in[8];
  const float* Wo      = (const float*)d_in[9];
  const float* bo      = (const float*)d_in[10];
  const float* ln2_g   = (const float*)d_in[11];
  const float* ln2_b   = (const float*)d_in[12];
  const float* W1      = (const float*)d_in[13];
  const float* b1      = (const float*)d_in[14];
  const float* W2      = (const float*)d_in[15];
  const float* b2      = (const float*)d_in[16];
  const float* lnf_g   = (const float*)d_in[17];
  const float* lnf_b   = (const float*)d_in[18];
  const float* Wout    = (const float*)d_in[19];
  const float* bout    = (const float*)d_in[20];

  char* p = (char*)d_ws;
  float* abuf = (float*)p;  p += (size_t)NB*NCONDV*4;
  float* gbuf = (float*)p;  p += (size_t)34*NB*ND*4;
  float* xbuf = (float*)p;  p += (size_t)NTOK*ND*4;
  u16*   hbuf = (u16*)p;    p += (size_t)NTOK*ND*2;
  u16*   region = (u16*)p;
  u16* qbuf = region;
  u16* kbuf = region + (size_t)NTOK*ND;
  u16* vbuf = region + (size_t)2*NTOK*ND;
  u16* obuf = (u16*)d_out;

  size_t base = (size_t)(p - (char*)d_ws) + (size_t)3*NTOK*ND*2;
  size_t hid_sz = (size_t)NTOK*3072*2;
  size_t woT_sz = (size_t)NL*ND*ND*2;
  size_t w1T_sz = (size_t)NL*ND*3072*2;
  size_t w2T_sz = (size_t)NL*3072*ND*2;
  size_t woutT_sz = (size_t)ND*NV*2;
  size_t req_fast = base + hid_sz + woT_sz + w1T_sz + w2T_sz + woutT_sz;
  const bool fast = (ws_size >= req_fast);

  k_embed <<<NTOK, 256, 0, stream>>>(tokens, emb, xbuf);
  k_actvec<<<NB, 256, 0, stream>>>(actions, act_emb, abuf);
  k_gains <<<dim3(34,3), 256, 0, stream>>>(abuf, ln1_g, ln1_b, ln2_g, ln2_b, lnf_g, lnf_b, gbuf);

  if (fast) {
    char* q2 = (char*)d_ws + base;
    u16* hidbuf = (u16*)q2;  q2 += hid_sz;
    u16* WoT   = (u16*)q2;   q2 += woT_sz;
    u16* W1T   = (u16*)q2;   q2 += w1T_sz;
    u16* W2T   = (u16*)q2;   q2 += w2T_sz;
    u16* WoutT = (u16*)q2;

    k_wprep<<<dim3(ND/64, ND/64, NL), 256, 0, stream>>>(Wo, WoT, ND, ND);
    k_wprep<<<dim3(ND/64, 3072/64, NL), 256, 0, stream>>>(W1, W1T, ND, 3072);
    k_wprep<<<dim3(3072/64, ND/64, NL), 256, 0, stream>>>(W2, W2T, 3072, ND);
    k_wprep<<<dim3(ND/64, NV/64, 1), 256, 0, stream>>>(Wout, WoutT, ND, NV);

    for (int l = 0; l < NL; l++) {
      k_cln<<<NTOK/4, 256, 0, stream>>>(xbuf, gbuf + (size_t)(l*4+0)*NB*ND, gbuf + (size_t)(l*4+1)*NB*ND, hbuf);
      k_qkv<<<dim3(NTOK/64, NH, 3), 256, 0, stream>>>(hbuf,
          Wq + (size_t)l*NH*NDH*NDH, Wk + (size_t)l*NH*NDH*NDH, Wv + (size_t)l*NH*NDH*NDH,
          qbuf, kbuf, vbuf);
      k_attn2<<<dim3(NB*NH, NS/64), 256, 0, stream>>>(qbuf, kbuf, vbuf, obuf);
      k_gemm_t<2><<<dim3(NTOK/128, ND/128), 256, 0, stream>>>(obuf, WoT + (size_t)l*ND*ND,
          bo + (size_t)l*ND, xbuf, xbuf, NTOK, ND, ND);
      k_cln<<<NTOK/4, 256, 0, stream>>>(xbuf, gbuf + (size_t)(l*4+2)*NB*ND, gbuf + (size_t)(l*4+3)*NB*ND, hbuf);
      k_gemm_t<1><<<dim3(NTOK/128, 3072/128), 256, 0, stream>>>(hbuf, W1T + (size_t)l*ND*3072,
          b1 + (size_t)l*3072, nullptr, hidbuf, NTOK, 3072, ND);
      k_gemm_t<2><<<dim3(NTOK/128, ND/128), 256, 0, stream>>>(hidbuf, W2T + (size_t)l*3072*ND,
          b2 + (size_t)l*ND, xbuf, xbuf, NTOK, ND, 3072);
    }
    k_cln<<<NTOK/4, 256, 0, stream>>>(xbuf, gbuf + (size_t)32*NB*ND, gbuf + (size_t)33*NB*ND, hbuf);
    k_gemm_t<0><<<dim3(NTOK/128, NV/128), 256, 0, stream>>>(hbuf, WoutT, bout, nullptr, (float*)d_out, NTOK, NV, ND);
  } else {
    u16* hidbuf = region;
    for (int l = 0; l < NL; l++) {
      k_cln<<<NTOK/4, 256, 0, stream>>>(xbuf, gbuf + (size_t)(l*4+0)*NB*ND, gbuf + (size_t)(l*4+1)*NB*ND, hbuf);
      k_qkv<<<dim3(NTOK/64, NH, 3), 256, 0, stream>>>(hbuf,
          Wq + (size_t)l*NH*NDH*NDH, Wk + (size_t)l*NH*NDH*NDH, Wv + (size_t)l*NH*NDH*NDH,
          qbuf, kbuf, vbuf);
      k_attn2<<<dim3(NB*NH, NS/64), 256, 0, stream>>>(qbuf, kbuf, vbuf, obuf);
      k_gemm<2><<<dim3(NTOK/64, ND/64), 256, 0, stream>>>(obuf, Wo + (size_t)l*ND*ND,
          bo + (size_t)l*ND, xbuf, xbuf, NTOK, ND, ND);
      k_cln<<<NTOK/4, 256, 0, stream>>>(xbuf, gbuf + (size_t)(l*4+2)*NB*ND, gbuf + (size_t)(l*4+3)*NB*ND, hbuf);
      for (int c = 0; c < 2; c++) {
        const size_t mo = (size_t)c * 4096;
        k_gemm<1><<<dim3(4096/64, 3072/64), 256, 0, stream>>>(hbuf + mo*ND, W1 + (size_t)l*ND*3072,
            b1 + (size_t)l*3072, nullptr, hidbuf, 4096, 3072, ND);
        k_gemm<2><<<dim3(4096/64, ND/64), 256, 0, stream>>>(hidbuf, W2 + (size_t)l*3072*ND,
            b2 + (size_t)l*ND, xbuf + mo*ND, xbuf + mo*ND, 4096, ND, 3072);
      }
    }
    k_cln<<<NTOK/4, 256, 0, stream>>>(xbuf, gbuf + (size_t)32*NB*ND, gbuf + (size_t)33*NB*ND, hbuf);
    k_gemm<0><<<dim3(NTOK/64, NV/64), 256, 0, stream>>>(hbuf, Wout, bout, nullptr, (float*)d_out, NTOK, NV, ND);
  }
}

// Round 6
// 2804.676 us; speedup vs baseline: 1.0594x; 1.0594x over previous
//
#include <hip/hip_runtime.h>
#include <hip/hip_bf16.h>

typedef unsigned short u16;
typedef __attribute__((ext_vector_type(8))) short bf16x8;
typedef __attribute__((ext_vector_type(4))) float f32x4;

#define NB 8
#define NS 1024
#define ND 768
#define NH 12
#define NL 8
#define NDH 64
#define NV 1024
#define NCONDV 256
#define NTOK (NB*NS)

union BF8 { bf16x8 v; u16 u[8]; };
union US4 { ushort4 v; u16 u[4]; };

__device__ __forceinline__ float b2f(u16 u){ return __uint_as_float(((unsigned)u) << 16); }
__device__ __forceinline__ u16 f2b(float f){
  unsigned u = __float_as_uint(f);
  return (u16)((u + 0x7fffu + ((u >> 16) & 1u)) >> 16);   // RNE, finite inputs only
}

__device__ __forceinline__ void glds16(const u16* g, u16* l) {
  __builtin_amdgcn_global_load_lds((const __attribute__((address_space(1))) void*)g,
                                   (__attribute__((address_space(3))) void*)l, 16, 0, 0);
}

// ---------------- embedding + sinusoidal PE -> x fp32 ----------------
__global__ __launch_bounds__(256) void k_embed(const int* __restrict__ tokens,
                                               const float* __restrict__ emb,
                                               float* __restrict__ x)
{
  const int t = blockIdx.x;
  const int s = t & (NS - 1);
  const int tok = tokens[t];
  const float c = (float)(-9.210340371976184 / 768.0);
  for (int d = threadIdx.x; d < ND; d += 256) {
    float div = expf((float)(d & ~1) * c);
    float ang = (float)s * div;
    float pe = (d & 1) ? cosf(ang) : sinf(ang);
    x[(size_t)t*ND + d] = emb[(size_t)tok*ND + d] + pe;
  }
}

// ---------------- action vector ----------------
__global__ __launch_bounds__(256) void k_actvec(const int* __restrict__ actions,
                                                const float* __restrict__ act_emb,
                                                float* __restrict__ a)
{
  const int b = blockIdx.x, j = threadIdx.x;
  const int i = j >> 6, kk = j & 63;
  const int act = actions[b*4 + i];
  a[b*NCONDV + j] = act_emb[(size_t)act*64 + kk];
}

// ---------------- conditional LN gains ----------------
__global__ __launch_bounds__(256) void k_gains(const float* __restrict__ a,
    const float* __restrict__ g1, const float* __restrict__ b1,
    const float* __restrict__ g2, const float* __restrict__ b2,
    const float* __restrict__ gf, const float* __restrict__ bfp,
    float* __restrict__ outp)
{
  __shared__ float sa[NB*NCONDV];
  const int m = blockIdx.x, dc = blockIdx.y;
  for (int i = threadIdx.x; i < NB*NCONDV; i += 256) sa[i] = a[i];
  __syncthreads();
  const float* W;
  if (m < 32) {
    int ll = m >> 2, w = m & 3;
    const float* base = (w==0) ? g1 : (w==1) ? b1 : (w==2) ? g2 : b2;
    W = base + (size_t)ll * NCONDV * ND;
  } else {
    W = (m == 32) ? gf : bfp;
  }
  const int d = dc*256 + threadIdx.x;
  float acc[NB] = {0,0,0,0,0,0,0,0};
  for (int j = 0; j < NCONDV; j++) {
    float w = W[(size_t)j*ND + d];
    #pragma unroll
    for (int bb = 0; bb < NB; bb++) acc[bb] += sa[bb*NCONDV + j] * w;
  }
  #pragma unroll
  for (int bb = 0; bb < NB; bb++) outp[((size_t)m*NB + bb)*ND + d] = acc[bb];
}

// ---------------- conditional layernorm: one wave per token, no barriers ----------------
__global__ __launch_bounds__(256) void k_cln(const float* __restrict__ x,
                                             const float* __restrict__ g,
                                             const float* __restrict__ bb,
                                             u16* __restrict__ h)
{
  const int tid = threadIdx.x, w = tid >> 6, lane = tid & 63;
  const int t = blockIdx.x*4 + w;
  const int bi = t >> 10;
  const float* xr = x + (size_t)t*ND;
  f32x4 v0 = *(const f32x4*)(xr + lane*4);
  f32x4 v1 = *(const f32x4*)(xr + 256 + lane*4);
  f32x4 v2 = *(const f32x4*)(xr + 512 + lane*4);
  float s = (v0[0]+v0[1]+v0[2]+v0[3]) + (v1[0]+v1[1]+v1[2]+v1[3]) + (v2[0]+v2[1]+v2[2]+v2[3]);
  #pragma unroll
  for (int off = 1; off < 64; off <<= 1) s += __shfl_xor(s, off);
  float mu = s * (1.0f/768.0f);
  float s2 = 0.f;
  #pragma unroll
  for (int i = 0; i < 4; i++) { v0[i] -= mu; s2 += v0[i]*v0[i]; }
  #pragma unroll
  for (int i = 0; i < 4; i++) { v1[i] -= mu; s2 += v1[i]*v1[i]; }
  #pragma unroll
  for (int i = 0; i < 4; i++) { v2[i] -= mu; s2 += v2[i]*v2[i]; }
  #pragma unroll
  for (int off = 1; off < 64; off <<= 1) s2 += __shfl_xor(s2, off);
  float rs = rsqrtf(s2 * (1.0f/768.0f) + 1e-5f);
  const float* gr = g + (size_t)bi*ND;
  const float* br = bb + (size_t)bi*ND;
  u16* hr = h + (size_t)t*ND;
  #pragma unroll
  for (int j = 0; j < 3; j++) {
    f32x4 vv = (j==0) ? v0 : (j==1) ? v1 : v2;
    f32x4 gg = *(const f32x4*)(gr + j*256 + lane*4);
    f32x4 bv = *(const f32x4*)(br + j*256 + lane*4);
    US4 o;
    #pragma unroll
    for (int i = 0; i < 4; i++) o.u[i] = f2b(vv[i]*rs*gg[i] + bv[i]);
    *(ushort4*)(hr + j*256 + lane*4) = o.v;
  }
}

// ---------------- weight prep: fp32 [K][N] (xL) -> bf16 [N][K] ----------------
__global__ __launch_bounds__(256) void k_wprep(const float* __restrict__ src,
                                               u16* __restrict__ dst, int K, int N)
{
  __shared__ u16 t[64][65];
  const int k0 = blockIdx.x*64, n0 = blockIdx.y*64;
  const size_t mz = (size_t)blockIdx.z * K * N;
  src += mz; dst += mz;
  {
    int r = threadIdx.x >> 2, c0 = (threadIdx.x & 3) * 16;
    const float* s = src + (size_t)(k0 + r)*N + n0 + c0;
    f32x4 a = *(const f32x4*)s, b = *(const f32x4*)(s+4);
    f32x4 c = *(const f32x4*)(s+8), d = *(const f32x4*)(s+12);
    #pragma unroll
    for (int i = 0; i < 4; i++) {
      t[r][c0+i]    = f2b(a[i]);
      t[r][c0+4+i]  = f2b(b[i]);
      t[r][c0+8+i]  = f2b(c[i]);
      t[r][c0+12+i] = f2b(d[i]);
    }
  }
  __syncthreads();
  {
    int rn = threadIdx.x >> 2, kc = (threadIdx.x & 3)*16;
    u16* dp = dst + (size_t)(n0+rn)*K + k0 + kc;
    BF8 o0, o1;
    #pragma unroll
    for (int i = 0; i < 8; i++) { o0.u[i] = t[kc+i][rn]; o1.u[i] = t[kc+8+i][rn]; }
    *(bf16x8*)dp = o0.v; *(bf16x8*)(dp+8) = o1.v;
  }
}

// ---------------- per-head QKV projection (fp32 weights) ----------------
__global__ __launch_bounds__(256) void k_qkv(const u16* __restrict__ h,
    const float* __restrict__ Wq, const float* __restrict__ Wk, const float* __restrict__ Wv,
    u16* __restrict__ qo, u16* __restrict__ ko, u16* __restrict__ vo)
{
  __shared__ alignas(16) u16 wlds[64][72];
  const int t0 = blockIdx.x * 64, head = blockIdx.y, which = blockIdx.z;
  const float* W = ((which==0) ? Wq : (which==1) ? Wk : Wv) + (size_t)head*NDH*NDH;
  {
    int d = threadIdx.x >> 2, e0 = (threadIdx.x & 3) * 16;
    const float* wr = W + (size_t)d*NDH + e0;
    f32x4 f0 = *(const f32x4*)wr;
    f32x4 f1 = *(const f32x4*)(wr + 4);
    f32x4 f2 = *(const f32x4*)(wr + 8);
    f32x4 f3 = *(const f32x4*)(wr + 12);
    #pragma unroll
    for (int i = 0; i < 4; i++) {
      wlds[e0+i][d]    = f2b(f0[i]);
      wlds[e0+4+i][d]  = f2b(f1[i]);
      wlds[e0+8+i][d]  = f2b(f2[i]);
      wlds[e0+12+i][d] = f2b(f3[i]);
    }
  }
  __syncthreads();
  const int wave = threadIdx.x >> 6, lane = threadIdx.x & 63;
  const int lo16 = lane & 15, quad = lane >> 4;
  const int arow = t0 + wave*16 + lo16;
  const u16* hr = h + (size_t)arow*ND + head*NDH + quad*8;
  bf16x8 a0 = *(const bf16x8*)hr;
  bf16x8 a1 = *(const bf16x8*)(hr + 32);
  f32x4 acc[4] = {{0,0,0,0},{0,0,0,0},{0,0,0,0},{0,0,0,0}};
  #pragma unroll
  for (int n = 0; n < 4; n++) {
    const u16* bp = &wlds[n*16 + lo16][quad*8];
    bf16x8 b0 = *(const bf16x8*)bp;
    bf16x8 b1 = *(const bf16x8*)(bp + 32);
    acc[n] = __builtin_amdgcn_mfma_f32_16x16x32_bf16(a0, b0, acc[n], 0, 0, 0);
    acc[n] = __builtin_amdgcn_mfma_f32_16x16x32_bf16(a1, b1, acc[n], 0, 0, 0);
  }
  #pragma unroll
  for (int n = 0; n < 4; n++) {
    #pragma unroll
    for (int r = 0; r < 4; r++) {
      int t = t0 + wave*16 + quad*4 + r;
      int bb = t >> 10, s = t & (NS-1);
      int e = n*16 + lo16;
      u16 val = f2b(acc[n][r]);
      if (which == 2) {
        int local = s & 127;
        int col = (s & ~127) | (((local & 15) << 3) | (local >> 4));
        vo[(((size_t)bb*NH + head)*NDH + e)*NS + col] = val;
      } else {
        u16* dst = (which == 0) ? qo : ko;
        dst[(((size_t)bb*NH + head)*NS + s)*NDH + e] = val;
      }
    }
  }
}

// ---------------- flash attention: no-max softmax, slot-permuted P/V ----------------
__global__ __launch_bounds__(256) void k_attn2(const u16* __restrict__ q,
                                               const u16* __restrict__ kk,
                                               const u16* __restrict__ vt,
                                               u16* __restrict__ o)
{
  __shared__ alignas(16) u16 klds[128][72];
  __shared__ alignas(16) u16 vlds[64][136];
  __shared__ alignas(16) u16 plds[4][16][136];
  const int tid = threadIdx.x, w = tid >> 6, lane = tid & 63;
  const int lo16 = lane & 15, quad = lane >> 4;
  const int bh = blockIdx.x;
  const int b = bh / NH, head = bh - b*NH;
  const int q0 = blockIdx.y*64 + w*16;
  const u16* qb = q  + (size_t)bh*NS*NDH;
  const u16* kb = kk + (size_t)bh*NS*NDH;
  const u16* vb = vt + (size_t)bh*NDH*NS;
  BF8 aq0, aq1;
  {
    const u16* qr = qb + (size_t)(q0 + lo16)*NDH + quad*8;
    BF8 r0, r1; r0.v = *(const bf16x8*)qr; r1.v = *(const bf16x8*)(qr + 32);
    #pragma unroll
    for (int j = 0; j < 8; j++) {
      aq0.u[j] = f2b(b2f(r0.u[j]) * 0.125f);
      aq1.u[j] = f2b(b2f(r1.u[j]) * 0.125f);
    }
  }
  float lsum[4] = {0,0,0,0};
  f32x4 oacc[4] = {{0,0,0,0},{0,0,0,0},{0,0,0,0},{0,0,0,0}};

  for (int kt = 0; kt < NS; kt += 128) {
    __syncthreads();
    #pragma unroll
    for (int i = 0; i < 4; i++) {
      int c = tid + 256*i, row = c >> 3, cc = (c & 7)*8;
      *(bf16x8*)&klds[row][cc] = *(const bf16x8*)(kb + (size_t)(kt+row)*NDH + cc);
    }
    #pragma unroll
    for (int i = 0; i < 4; i++) {
      int c = tid + 256*i, row = c >> 4, cc = (c & 15)*8;
      *(bf16x8*)&vlds[row][cc] = *(const bf16x8*)(vb + (size_t)row*NS + kt + cc);
    }
    __syncthreads();
    f32x4 s[8];
    #pragma unroll
    for (int j = 0; j < 8; j++) {
      const u16* kr = &klds[j*16 + lo16][quad*8];
      bf16x8 b0 = *(const bf16x8*)kr;
      bf16x8 b1 = *(const bf16x8*)(kr + 32);
      f32x4 z = {0,0,0,0};
      z = __builtin_amdgcn_mfma_f32_16x16x32_bf16(aq0.v, b0, z, 0, 0, 0);
      s[j] = __builtin_amdgcn_mfma_f32_16x16x32_bf16(aq1.v, b1, z, 0, 0, 0);
    }
    #pragma unroll
    for (int r = 0; r < 4; r++) {
      BF8 pk;
      float ps = 0.f;
      #pragma unroll
      for (int j = 0; j < 8; j++) {
        float pj = __expf(s[j][r]);
        pk.u[j] = f2b(pj);
        ps += b2f(pk.u[j]);
      }
      lsum[r] += ps;
      *(bf16x8*)&plds[w][quad*4 + r][lo16*8] = pk.v;
    }
    #pragma unroll
    for (int kc = 0; kc < 4; kc++) {
      bf16x8 pa = *(const bf16x8*)&plds[w][lo16][kc*32 + quad*8];
      #pragma unroll
      for (int n = 0; n < 4; n++) {
        bf16x8 vf = *(const bf16x8*)&vlds[n*16 + lo16][kc*32 + quad*8];
        oacc[n] = __builtin_amdgcn_mfma_f32_16x16x32_bf16(pa, vf, oacc[n], 0, 0, 0);
      }
    }
  }
  #pragma unroll
  for (int r = 0; r < 4; r++) {
    #pragma unroll
    for (int off = 1; off < 16; off <<= 1) lsum[r] += __shfl_xor(lsum[r], off);
  }
  #pragma unroll
  for (int n = 0; n < 4; n++) {
    #pragma unroll
    for (int r = 0; r < 4; r++) {
      int s_ = q0 + quad*4 + r;
      int d = head*NDH + n*16 + lo16;
      o[((size_t)b*NS + s_)*ND + d] = f2b(oacc[n][r] / lsum[r]);
    }
  }
}

// ---------------- fast GEMM: MTx128 tile, BK=64 via two 32-k half-buffers ----------------
// Each half-buffer keeps m97's 64B row stride (lane-contiguous staging, proven bank pattern).
// MT=128: 4 waves 2x2 (64x64/wave, 32 MFMA/barrier). MT=64: waves 32x64, more blocks for small-N GEMMs.
// Bt is bf16 [N][K]. EPI 0: f32=A@B+bias ; 1: bf16=gelu(A@B+bias) ; 2: f32=A@B+bias+resid
template<int EPI, int MT>
__global__ __launch_bounds__(256) void k_gemm_t(
    const u16* __restrict__ A, const u16* __restrict__ Bt,
    const float* __restrict__ bias, const float* resid,
    void* out, int M, int N, int K)
{
  constexpr int MI = MT/32;                     // m-frags per wave
  __shared__ alignas(16) u16 alds[2*MT*32];     // [half][m][k32], 64B row stride
  __shared__ alignas(16) u16 blds[2*128*32];    // [half][n][k32]
  const int m0 = blockIdx.x*MT, n0 = blockIdx.y*128;
  const int tid = threadIdx.x;
  const int w = tid >> 6, lane = tid & 63, lo16 = lane & 15, quad = lane >> 4;
  const int wm = (w & 1)*(MT/2), wn = (w >> 1)*64;
  f32x4 acc[MI][4];
  #pragma unroll
  for (int i = 0; i < MI; i++)
    #pragma unroll
    for (int j = 0; j < 4; j++) acc[i][j] = (f32x4){0,0,0,0};
  const int r0 = tid >> 2, c0 = (tid & 3)*8;    // staging: row, k-offset within 32-k half
  const u16* Ap = A  + (size_t)(m0 + r0)*K + c0;
  const u16* Bp = Bt + (size_t)(n0 + r0)*K + c0;
  for (int k0 = 0; k0 < K; k0 += 64) {
    __syncthreads();
    #pragma unroll
    for (int h = 0; h < 2; h++) {
      const int ho = h*32;
      glds16(Ap + k0 + ho, alds + h*(MT*32) + tid*8);
      if (MT == 128) glds16(Ap + (size_t)64*K + k0 + ho, alds + h*(MT*32) + 2048 + tid*8);
      glds16(Bp + k0 + ho, blds + h*4096 + tid*8);
      glds16(Bp + (size_t)64*K + k0 + ho, blds + h*4096 + 2048 + tid*8);
    }
    __syncthreads();
    #pragma unroll
    for (int h = 0; h < 2; h++) {
      const u16* ah = alds + h*(MT*32);
      const u16* bh = blds + h*4096;
      bf16x8 af[MI], bf[4];
      #pragma unroll
      for (int i = 0; i < MI; i++) af[i] = *(const bf16x8*)&ah[(wm + i*16 + lo16)*32 + quad*8];
      #pragma unroll
      for (int j = 0; j < 4; j++) bf[j] = *(const bf16x8*)&bh[(wn + j*16 + lo16)*32 + quad*8];
      #pragma unroll
      for (int i = 0; i < MI; i++)
        #pragma unroll
        for (int j = 0; j < 4; j++)
          acc[i][j] = __builtin_amdgcn_mfma_f32_16x16x32_bf16(af[i], bf[j], acc[i][j], 0, 0, 0);
    }
  }
  #pragma unroll
  for (int j = 0; j < 4; j++) {
    int col = n0 + wn + j*16 + lo16;
    float bv = bias[col];
    #pragma unroll
    for (int i = 0; i < MI; i++) {
      #pragma unroll
      for (int r = 0; r < 4; r++) {
        int row = m0 + wm + i*16 + quad*4 + r;
        float v = acc[i][j][r] + bv;
        if (EPI == 1) {
          float u = 0.7978845608028654f*(v + 0.044715f*v*v*v);
          float e = __expf(2.0f*u);
          float th = (e - 1.0f) / (e + 1.0f);
          ((u16*)out)[(size_t)row*N + col] = f2b(0.5f*v*(1.0f + th));
        } else if (EPI == 2) {
          ((float*)out)[(size_t)row*N + col] = v + resid[(size_t)row*N + col];
        } else {
          ((float*)out)[(size_t)row*N + col] = v;
        }
      }
    }
  }
}

// ---------------- fallback GEMM (fp32 weights, 64x64 tile) ----------------
template<int EPI>
__global__ __launch_bounds__(256) void k_gemm(
    const u16* __restrict__ A, const float* __restrict__ Bw,
    const float* __restrict__ bias, const float* resid,
    void* out, int M, int N, int K)
{
  __shared__ alignas(16) u16 alds[64][40];
  __shared__ alignas(16) u16 blds[64][40];
  const int m0 = blockIdx.x * 64, n0b = blockIdx.y * 64;
  const int tid = threadIdx.x;
  const int wave = tid >> 6, lane = tid & 63, lo16 = lane & 15, quad = lane >> 4;
  f32x4 acc[4] = {{0,0,0,0},{0,0,0,0},{0,0,0,0},{0,0,0,0}};
  const int ar = tid >> 2, ac = (tid & 3) * 8;
  const int bk = tid >> 3, bn = (tid & 7) * 8;
  for (int k0 = 0; k0 < K; k0 += 32) {
    __syncthreads();
    *(bf16x8*)&alds[ar][ac] = *(const bf16x8*)(A + (size_t)(m0+ar)*K + k0 + ac);
    {
      const float* brow = Bw + (size_t)(k0+bk)*N + n0b + bn;
      f32x4 f0 = *(const f32x4*)brow;
      f32x4 f1 = *(const f32x4*)(brow + 4);
      #pragma unroll
      for (int i = 0; i < 4; i++) {
        blds[bn+i][bk]   = f2b(f0[i]);
        blds[bn+4+i][bk] = f2b(f1[i]);
      }
    }
    __syncthreads();
    bf16x8 af = *(const bf16x8*)&alds[wave*16 + lo16][quad*8];
    #pragma unroll
    for (int n = 0; n < 4; n++) {
      bf16x8 bf = *(const bf16x8*)&blds[n*16 + lo16][quad*8];
      acc[n] = __builtin_amdgcn_mfma_f32_16x16x32_bf16(af, bf, acc[n], 0, 0, 0);
    }
  }
  const int rbase = m0 + wave*16 + quad*4;
  #pragma unroll
  for (int n = 0; n < 4; n++) {
    int col = n0b + n*16 + lo16;
    float bv = bias[col];
    #pragma unroll
    for (int r = 0; r < 4; r++) {
      int row = rbase + r;
      float v = acc[n][r] + bv;
      if (EPI == 1) {
        float x3 = v*v*v;
        v = 0.5f*v*(1.0f + tanhf(0.7978845608028654f*(v + 0.044715f*x3)));
        ((u16*)out)[(size_t)row*N + col] = f2b(v);
      } else if (EPI == 2) {
        ((float*)out)[(size_t)row*N + col] = v + resid[(size_t)row*N + col];
      } else {
        ((float*)out)[(size_t)row*N + col] = v;
      }
    }
  }
}

extern "C" void kernel_launch(void* const* d_in, const int* in_sizes, int n_in,
                              void* d_out, int out_size, void* d_ws, size_t ws_size,
                              hipStream_t stream)
{
  (void)in_sizes; (void)n_in; (void)out_size;
  const int*   tokens  = (const int*)d_in[0];
  const int*   actions = (const int*)d_in[1];
  const float* emb     = (const float*)d_in[2];
  const float* act_emb = (const float*)d_in[3];
  const float* ln1_g   = (const float*)d_in[4];
  const float* ln1_b   = (const float*)d_in[5];
  const float* Wq      = (const float*)d_in[6];
  const float* Wk      = (const float*)d_in[7];
  const float* Wv      = (const float*)d_in[8];
  const float* Wo      = (const float*)d_in[9];
  const float* bo      = (const float*)d_in[10];
  const float* ln2_g   = (const float*)d_in[11];
  const float* ln2_b   = (const float*)d_in[12];
  const float* W1      = (const float*)d_in[13];
  const float* b1      = (const float*)d_in[14];
  const float* W2      = (const float*)d_in[15];
  const float* b2      = (const float*)d_in[16];
  const float* lnf_g   = (const float*)d_in[17];
  const float* lnf_b   = (const float*)d_in[18];
  const float* Wout    = (const float*)d_in[19];
  const float* bout    = (const float*)d_in[20];

  char* p = (char*)d_ws;
  float* abuf = (float*)p;  p += (size_t)NB*NCONDV*4;
  float* gbuf = (float*)p;  p += (size_t)34*NB*ND*4;
  float* xbuf = (float*)p;  p += (size_t)NTOK*ND*4;
  u16*   hbuf = (u16*)p;    p += (size_t)NTOK*ND*2;
  u16*   region = (u16*)p;
  u16* qbuf = region;
  u16* kbuf = region + (size_t)NTOK*ND;
  u16* vbuf = region + (size_t)2*NTOK*ND;
  u16* obuf = (u16*)d_out;

  size_t base = (size_t)(p - (char*)d_ws) + (size_t)3*NTOK*ND*2;
  size_t hid_sz = (size_t)NTOK*3072*2;
  size_t woT_sz = (size_t)NL*ND*ND*2;
  size_t w1T_sz = (size_t)NL*ND*3072*2;
  size_t w2T_sz = (size_t)NL*3072*ND*2;
  size_t woutT_sz = (size_t)ND*NV*2;
  size_t req_fast = base + hid_sz + woT_sz + w1T_sz + w2T_sz + woutT_sz;
  const bool fast = (ws_size >= req_fast);

  k_embed <<<NTOK, 256, 0, stream>>>(tokens, emb, xbuf);
  k_actvec<<<NB, 256, 0, stream>>>(actions, act_emb, abuf);
  k_gains <<<dim3(34,3), 256, 0, stream>>>(abuf, ln1_g, ln1_b, ln2_g, ln2_b, lnf_g, lnf_b, gbuf);

  if (fast) {
    char* q2 = (char*)d_ws + base;
    u16* hidbuf = (u16*)q2;  q2 += hid_sz;
    u16* WoT   = (u16*)q2;   q2 += woT_sz;
    u16* W1T   = (u16*)q2;   q2 += w1T_sz;
    u16* W2T   = (u16*)q2;   q2 += w2T_sz;
    u16* WoutT = (u16*)q2;

    k_wprep<<<dim3(ND/64, ND/64, NL), 256, 0, stream>>>(Wo, WoT, ND, ND);
    k_wprep<<<dim3(ND/64, 3072/64, NL), 256, 0, stream>>>(W1, W1T, ND, 3072);
    k_wprep<<<dim3(3072/64, ND/64, NL), 256, 0, stream>>>(W2, W2T, 3072, ND);
    k_wprep<<<dim3(ND/64, NV/64, 1), 256, 0, stream>>>(Wout, WoutT, ND, NV);

    for (int l = 0; l < NL; l++) {
      k_cln<<<NTOK/4, 256, 0, stream>>>(xbuf, gbuf + (size_t)(l*4+0)*NB*ND, gbuf + (size_t)(l*4+1)*NB*ND, hbuf);
      k_qkv<<<dim3(NTOK/64, NH, 3), 256, 0, stream>>>(hbuf,
          Wq + (size_t)l*NH*NDH*NDH, Wk + (size_t)l*NH*NDH*NDH, Wv + (size_t)l*NH*NDH*NDH,
          qbuf, kbuf, vbuf);
      k_attn2<<<dim3(NB*NH, NS/64), 256, 0, stream>>>(qbuf, kbuf, vbuf, obuf);
      k_gemm_t<2,64><<<dim3(NTOK/64, ND/128), 256, 0, stream>>>(obuf, WoT + (size_t)l*ND*ND,
          bo + (size_t)l*ND, xbuf, xbuf, NTOK, ND, ND);
      k_cln<<<NTOK/4, 256, 0, stream>>>(xbuf, gbuf + (size_t)(l*4+2)*NB*ND, gbuf + (size_t)(l*4+3)*NB*ND, hbuf);
      k_gemm_t<1,128><<<dim3(NTOK/128, 3072/128), 256, 0, stream>>>(hbuf, W1T + (size_t)l*ND*3072,
          b1 + (size_t)l*3072, nullptr, hidbuf, NTOK, 3072, ND);
      k_gemm_t<2,64><<<dim3(NTOK/64, ND/128), 256, 0, stream>>>(hidbuf, W2T + (size_t)l*3072*ND,
          b2 + (size_t)l*ND, xbuf, xbuf, NTOK, ND, 3072);
    }
    k_cln<<<NTOK/4, 256, 0, stream>>>(xbuf, gbuf + (size_t)32*NB*ND, gbuf + (size_t)33*NB*ND, hbuf);
    k_gemm_t<0,64><<<dim3(NTOK/64, NV/128), 256, 0, stream>>>(hbuf, WoutT, bout, nullptr, (float*)d_out, NTOK, NV, ND);
  } else {
    u16* hidbuf = region;
    for (int l = 0; l < NL; l++) {
      k_cln<<<NTOK/4, 256, 0, stream>>>(xbuf, gbuf + (size_t)(l*4+0)*NB*ND, gbuf + (size_t)(l*4+1)*NB*ND, hbuf);
      k_qkv<<<dim3(NTOK/64, NH, 3), 256, 0, stream>>>(hbuf,
          Wq + (size_t)l*NH*NDH*NDH, Wk + (size_t)l*NH*NDH*NDH, Wv + (size_t)l*NH*NDH*NDH,
          qbuf, kbuf, vbuf);
      k_attn2<<<dim3(NB*NH, NS/64), 256, 0, stream>>>(qbuf, kbuf, vbuf, obuf);
      k_gemm<2><<<dim3(NTOK/64, ND/64), 256, 0, stream>>>(obuf, Wo + (size_t)l*ND*ND,
          bo + (size_t)l*ND, xbuf, xbuf, NTOK, ND, ND);
      k_cln<<<NTOK/4, 256, 0, stream>>>(xbuf, gbuf + (size_t)(l*4+2)*NB*ND, gbuf + (size_t)(l*4+3)*NB*ND, hbuf);
      for (int c = 0; c < 2; c++) {
        const size_t mo = (size_t)c * 4096;
        k_gemm<1><<<dim3(4096/64, 3072/64), 256, 0, stream>>>(hbuf + mo*ND, W1 + (size_t)l*ND*3072,
            b1 + (size_t)l*3072, nullptr, hidbuf, 4096, 3072, ND);
        k_gemm<2><<<dim3(4096/64, ND/64), 256, 0, stream>>>(hidbuf, W2 + (size_t)l*3072*ND,
            b2 + (size_t)l*ND, xbuf + mo*ND, xbuf + mo*ND, 4096, ND, 3072);
      }
    }
    k_cln<<<NTOK/4, 256, 0, stream>>>(xbuf, gbuf + (size_t)32*NB*ND, gbuf + (size_t)33*NB*ND, hbuf);
    k_gemm<0><<<dim3(NTOK/64, NV/64), 256, 0, stream>>>(hbuf, Wout, bout, nullptr, (float*)d_out, NTOK, NV, ND);
  }
}